// Round 1
// baseline (17620.949 us; speedup 1.0000x reference)
//
#include <hip/hip_runtime.h>
#include <math.h>

#define B_ 32
#define T_ 512
#define D_ 512
#define H_ 512
#define G_ 2048        // 4*H
#define M_ (B_ * T_)   // 16384

__device__ __forceinline__ float sigmoidf_(float x) { return 1.0f / (1.0f + expf(-x)); }

// -----------------------------------------------------------------------------
// GEMM: xs[dir][m][g] = A_dir[m][:] @ Wi_dir + bias_dir
//   A_f[m][k] = x[b, t, k]                 (m = b*T + t)
//   A_b[m][k] = x[b, (l_b-1-t) mod T, k]   (gathered reversed sequence)
// Tiles: BM=64, BN=64, BK=32; 256 threads; 4x4 per thread.
// -----------------------------------------------------------------------------
__global__ __launch_bounds__(256) void xs_gemm(
    const float* __restrict__ x, const int* __restrict__ lengths,
    const float* __restrict__ Wi_f, const float* __restrict__ bf,
    const float* __restrict__ Wi_b, const float* __restrict__ bb,
    float* __restrict__ xs)
{
  const int dir = blockIdx.z;
  const float* Wi   = dir ? Wi_b : Wi_f;
  const float* bias = dir ? bb : bf;
  float* outp = xs + (size_t)dir * ((size_t)M_ * G_);
  const int m0 = blockIdx.x * 64;
  const int n0 = blockIdx.y * 64;

  __shared__ __attribute__((aligned(16))) float As[32][68]; // [k][m], row=272B (16B-aligned)
  __shared__ __attribute__((aligned(16))) float Bs[32][68]; // [k][n]

  const int tid = threadIdx.x;
  const int tx = tid & 15, ty = tid >> 4;
  const int arow = tid >> 3;          // 0..31
  const int acol = (tid & 7) << 2;    // 0,4,..28
  const int brow = tid >> 4;          // 0..15
  const int bcol = (tid & 15) << 2;   // 0..60

  size_t abase[2];
#pragma unroll
  for (int r = 0; r < 2; ++r) {
    int m = m0 + arow + r * 32;
    int bidx = m >> 9, t = m & 511;
    int s = t;
    if (dir) { int l = lengths[bidx]; s = l - 1 - t; if (s < 0) s += T_; }
    abase[r] = ((size_t)bidx * T_ + s) * D_;
  }

  float acc[4][4] = {{0.f}};

  for (int k0 = 0; k0 < D_; k0 += 32) {
#pragma unroll
    for (int r = 0; r < 2; ++r) {
      float4 av = *(const float4*)(x + abase[r] + (k0 + acol));
      int row = arow + r * 32;
      As[acol + 0][row] = av.x;
      As[acol + 1][row] = av.y;
      As[acol + 2][row] = av.z;
      As[acol + 3][row] = av.w;
    }
#pragma unroll
    for (int r = 0; r < 2; ++r) {
      int kk = brow + r * 16;
      float4 bv = *(const float4*)(Wi + (size_t)(k0 + kk) * G_ + n0 + bcol);
      *(float4*)&Bs[kk][bcol] = bv;
    }
    __syncthreads();
#pragma unroll
    for (int kk = 0; kk < 32; ++kk) {
      float4 a4 = *(const float4*)&As[kk][ty << 2];
      float4 b4 = *(const float4*)&Bs[kk][tx << 2];
      float a_[4] = {a4.x, a4.y, a4.z, a4.w};
      float b_[4] = {b4.x, b4.y, b4.z, b4.w};
#pragma unroll
      for (int i = 0; i < 4; ++i)
#pragma unroll
        for (int j = 0; j < 4; ++j)
          acc[i][j] = fmaf(a_[i], b_[j], acc[i][j]);
    }
    __syncthreads();
  }

  float4 bias4 = *(const float4*)(bias + n0 + (tx << 2));
  float bb4[4] = {bias4.x, bias4.y, bias4.z, bias4.w};
#pragma unroll
  for (int i = 0; i < 4; ++i) {
    int m = m0 + (ty << 2) + i;
    float4 o;
    o.x = acc[i][0] + bb4[0];
    o.y = acc[i][1] + bb4[1];
    o.z = acc[i][2] + bb4[2];
    o.w = acc[i][3] + bb4[3];
    *(float4*)(outp + (size_t)m * G_ + n0 + (tx << 2)) = o;
  }
}

// -----------------------------------------------------------------------------
// Recurrence: one workgroup per (batch, dir); 512 threads; sync-free across WGs.
// h in LDS; c in a register (thread tid owns hidden unit tid).
// Matvec: thread q computes y[4q..4q+3] streaming Wh columns as float4.
// Output scatter handles the flip-back for the bwd direction.
// -----------------------------------------------------------------------------
__global__ __launch_bounds__(512) void lstm_rec(
    const float* __restrict__ xs, const float* __restrict__ Wh_f,
    const float* __restrict__ Wh_b, const int* __restrict__ lengths,
    float* __restrict__ out)
{
  const int b   = blockIdx.x >> 1;
  const int dir = blockIdx.x & 1;
  const float* Wh  = dir ? Wh_b : Wh_f;
  const float* xsd = xs + (size_t)dir * ((size_t)M_ * G_) + (size_t)b * T_ * G_;

  __shared__ __attribute__((aligned(16))) float h[H_];
  __shared__ __attribute__((aligned(16))) float y[G_];

  const int tid = threadIdx.x;
  float c = 0.f;
  h[tid] = 0.f;
  const int l = lengths[b];
  __syncthreads();

  for (int t = 0; t < T_; ++t) {
    const float* xrow = xsd + (size_t)t * G_;
    float4 acc = *(const float4*)(xrow + 4 * tid);
    const float* wp = Wh + 4 * tid;
#pragma unroll 8
    for (int k = 0; k < H_; ++k) {
      float hk = h[k];
      float4 w = *(const float4*)(wp + (size_t)k * G_);
      acc.x = fmaf(hk, w.x, acc.x);
      acc.y = fmaf(hk, w.y, acc.y);
      acc.z = fmaf(hk, w.z, acc.z);
      acc.w = fmaf(hk, w.w, acc.w);
    }
    *(float4*)(y + 4 * tid) = acc;
    __syncthreads();

    float iv = sigmoidf_(y[tid]);
    float fv = sigmoidf_(y[H_ + tid]);
    float gv = tanhf(y[2 * H_ + tid]);
    float ov = sigmoidf_(y[3 * H_ + tid]);
    c = fv * c + iv * gv;
    float hv = ov * tanhf(c);
    h[tid] = hv;  // all reads of h for this step completed before prior sync

    int tout = t;
    if (dir) { tout = l - 1 - t; if (tout < 0) tout += T_; }
    out[((size_t)b * T_ + tout) * (2 * H_) + dir * H_ + tid] = hv;
    __syncthreads();
  }
}

extern "C" void kernel_launch(void* const* d_in, const int* in_sizes, int n_in,
                              void* d_out, int out_size, void* d_ws, size_t ws_size,
                              hipStream_t stream) {
  const float* x       = (const float*)d_in[0];
  const int*   lengths = (const int*)d_in[1];
  const float* Wi_f    = (const float*)d_in[2];
  const float* Wh_f    = (const float*)d_in[3];
  const float* b_f     = (const float*)d_in[4];
  const float* Wi_b    = (const float*)d_in[5];
  const float* Wh_b    = (const float*)d_in[6];
  const float* b_b     = (const float*)d_in[7];
  float* out = (float*)d_out;
  float* xs  = (float*)d_ws;  // 2 * 16384 * 2048 fp32 = 256 MiB

  dim3 g1(M_ / 64, G_ / 64, 2);
  xs_gemm<<<g1, 256, 0, stream>>>(x, lengths, Wi_f, b_f, Wi_b, b_b, xs);
  lstm_rec<<<dim3(2 * B_), 512, 0, stream>>>(xs, Wh_f, Wh_b, lengths, out);
}